// Round 5
// baseline (2394.436 us; speedup 1.0000x reference)
//
#include <hip/hip_runtime.h>
#include <stdint.h>

// ---------------- problem constants (fixed by setup_inputs) ----------------
static constexpr int NN    = 32768;   // nodes
static constexpr int NPG   = 1024;    // nodes per graph
static constexpr int EPG   = 2048;    // edges per graph
static constexpr int NGR   = 32;      // graphs
static constexpr int NF    = 8;       // filtrations
static constexpr int FEAT  = 512;
static constexpr int ODIM  = 64;
static constexpr int ETOT  = NGR * EPG;

// order-preserving float -> uint key
__device__ __forceinline__ unsigned int fsort(float f) {
    unsigned int u = __float_as_uint(f);
    return (u & 0x80000000u) ? ~u : (u | 0x80000000u);
}

// ======================= 1. fv = relu(x@W1+b1)@W2+b2 =======================
// grid 512 blocks (64 rows each), 256 threads. f32 vector FMA.
// Writes fv row-major [N][8] (for feat_k) AND fvT col-major [8][N] (for uf).
__global__ __launch_bounds__(256, 2) void gemm_fv_k(
        const float* __restrict__ x,  const float* __restrict__ W1,
        const float* __restrict__ b1, const float* __restrict__ W2,
        const float* __restrict__ b2, float* __restrict__ fv,
        float* __restrict__ fvT) {
    __shared__ float As[64][68];   // As[k][r] transposed x tile
    __shared__ float Bs[64][68];   // Bs[k][c] W1 tile
    __shared__ float W2s[64][8];

    const int tid = threadIdx.x;
    const int tx = tid & 15;       // col group: cols tx*4..+3
    const int ty = tid >> 4;       // row group: rows ty*4..+3
    const int rowBase = blockIdx.x * 64;

    float fvacc[4][8];
#pragma unroll
    for (int r = 0; r < 4; ++r)
#pragma unroll
        for (int j = 0; j < 8; ++j) fvacc[r][j] = 0.f;

    for (int cc = 0; cc < 8; ++cc) {           // 64-col chunk of W1
        float hacc[4][4];
#pragma unroll
        for (int r = 0; r < 4; ++r)
#pragma unroll
            for (int c = 0; c < 4; ++c) hacc[r][c] = 0.f;

        for (int kt = 0; kt < 8; ++kt) {       // K tile of 64
#pragma unroll
            for (int p = 0; p < 4; ++p) {
                int fid = tid + p * 256;
                int rr = fid >> 4, c4 = fid & 15;
                float4 av = *(const float4*)&x[(size_t)(rowBase + rr) * FEAT + kt * 64 + c4 * 4];
                As[c4 * 4 + 0][rr] = av.x; As[c4 * 4 + 1][rr] = av.y;
                As[c4 * 4 + 2][rr] = av.z; As[c4 * 4 + 3][rr] = av.w;
                float4 bv = *(const float4*)&W1[(size_t)(kt * 64 + rr) * FEAT + cc * 64 + c4 * 4];
                *(float4*)&Bs[rr][c4 * 4] = bv;
            }
            if (kt == 0) {
#pragma unroll
                for (int p = 0; p < 2; ++p) {
                    int idx = tid + p * 256;          // 512 entries
                    int cw = idx >> 3, j = idx & 7;
                    W2s[cw][j] = W2[(cc * 64 + cw) * NF + j];
                }
            }
            __syncthreads();
#pragma unroll 8
            for (int kk = 0; kk < 64; ++kk) {
                float4 a4 = *(const float4*)&As[kk][ty * 4];
                float4 b4 = *(const float4*)&Bs[kk][tx * 4];
                hacc[0][0] += a4.x * b4.x; hacc[0][1] += a4.x * b4.y; hacc[0][2] += a4.x * b4.z; hacc[0][3] += a4.x * b4.w;
                hacc[1][0] += a4.y * b4.x; hacc[1][1] += a4.y * b4.y; hacc[1][2] += a4.y * b4.z; hacc[1][3] += a4.y * b4.w;
                hacc[2][0] += a4.z * b4.x; hacc[2][1] += a4.z * b4.y; hacc[2][2] += a4.z * b4.z; hacc[2][3] += a4.z * b4.w;
                hacc[3][0] += a4.w * b4.x; hacc[3][1] += a4.w * b4.y; hacc[3][2] += a4.w * b4.z; hacc[3][3] += a4.w * b4.w;
            }
            __syncthreads();
        }
        // relu(hacc + b1) @ W2 -> partial fv, reduced over the 16 tx lanes
        float4 b1v = *(const float4*)&b1[cc * 64 + tx * 4];
        float pf[4][8];
#pragma unroll
        for (int r = 0; r < 4; ++r)
#pragma unroll
            for (int j = 0; j < 8; ++j) pf[r][j] = 0.f;
#pragma unroll
        for (int c = 0; c < 4; ++c) {
            float bc = (c == 0) ? b1v.x : (c == 1) ? b1v.y : (c == 2) ? b1v.z : b1v.w;
            float4 w0 = *(const float4*)&W2s[tx * 4 + c][0];
            float4 w1 = *(const float4*)&W2s[tx * 4 + c][4];
#pragma unroll
            for (int r = 0; r < 4; ++r) {
                float h = fmaxf(hacc[r][c] + bc, 0.f);
                pf[r][0] += h * w0.x; pf[r][1] += h * w0.y; pf[r][2] += h * w0.z; pf[r][3] += h * w0.w;
                pf[r][4] += h * w1.x; pf[r][5] += h * w1.y; pf[r][6] += h * w1.z; pf[r][7] += h * w1.w;
            }
        }
#pragma unroll
        for (int m = 1; m <= 8; m <<= 1)
#pragma unroll
            for (int r = 0; r < 4; ++r)
#pragma unroll
                for (int j = 0; j < 8; ++j) pf[r][j] += __shfl_xor(pf[r][j], m);
#pragma unroll
        for (int r = 0; r < 4; ++r)
#pragma unroll
            for (int j = 0; j < 8; ++j) fvacc[r][j] += pf[r][j];
        __syncthreads();   // protect As/Bs/W2s before next chunk
    }
    if (tx == 0) {
        float b2a[8];
        *(float4*)&b2a[0] = *(const float4*)&b2[0];
        *(float4*)&b2a[4] = *(const float4*)&b2[4];
        float vals[4][8];
#pragma unroll
        for (int r = 0; r < 4; ++r)
#pragma unroll
            for (int j = 0; j < 8; ++j) vals[r][j] = fvacc[r][j] + b2a[j];
#pragma unroll
        for (int r = 0; r < 4; ++r) {
            int row = rowBase + ty * 4 + r;
            float4 o0 = { vals[r][0], vals[r][1], vals[r][2], vals[r][3] };
            float4 o1 = { vals[r][4], vals[r][5], vals[r][6], vals[r][7] };
            *(float4*)&fv[(size_t)row * NF + 0] = o0;
            *(float4*)&fv[(size_t)row * NF + 4] = o1;
        }
#pragma unroll
        for (int j = 0; j < 8; ++j) {
            float4 t = { vals[0][j], vals[1][j], vals[2][j], vals[3][j] };
            *(float4*)&fvT[(size_t)j * NN + rowBase + ty * 4] = t;
        }
    }
}

// ============ 2a. per-(graph,filtration) edge key build + bitonic sort ============
// grid 256 blocks (g = b>>3, k = b&7), 512 threads. Writes sorted uvw stream.
__global__ __launch_bounds__(512) void uf_sort_k(
        const float* __restrict__ fvT, const int* __restrict__ ei,
        unsigned int* __restrict__ suvw) {
    __shared__ float fvl[NPG];
    __shared__ unsigned long long keys[EPG];   // (fe_key<<32) | e  (stable tie-break)
    __shared__ unsigned int uvw[EPG];          // u | v<<10 | wflag<<20
    const int tid = threadIdx.x;
    const int g = blockIdx.x >> 3, k = blockIdx.x & 7;

    for (int i = tid; i < NPG; i += 512) fvl[i] = fvT[(size_t)k * NN + (g << 10) + i];
    __syncthreads();
    for (int e = tid; e < EPG; e += 512) {
        int eg = g * EPG + e;
        int u = ei[eg] & (NPG - 1);
        int v = ei[ETOT + eg] & (NPG - 1);
        unsigned int fku = fsort(fvl[u]);
        unsigned int fkv = fsort(fvl[v]);
        unsigned int wfl = (fku > fkv || (fku == fkv && u >= v)) ? 1u : 0u;  // w = u iff (fv[u],u) >= (fv[v],v)
        unsigned int fe = fku > fkv ? fku : fkv;
        uvw[e] = (unsigned)u | ((unsigned)v << 10) | (wfl << 20);
        keys[e] = ((unsigned long long)fe << 32) | (unsigned)e;
    }
    for (int size = 2; size <= EPG; size <<= 1) {
        for (int stride = size >> 1; stride > 0; stride >>= 1) {
            __syncthreads();
            for (int i = tid; i < EPG; i += 512) {
                int j = i ^ stride;
                if (j > i) {
                    unsigned long long a = keys[i], b = keys[j];
                    bool asc = (i & size) == 0;
                    if (asc ? (a > b) : (a < b)) { keys[i] = b; keys[j] = a; }
                }
            }
        }
    }
    __syncthreads();
    for (int i = tid; i < EPG; i += 512)
        suvw[(size_t)blockIdx.x * EPG + i] = uvw[(unsigned)(keys[i] & 0xffffffffULL)];
}

// ============ 2b. parallel union-find over the sorted stream ============
// grid 256 blocks, 512 threads; thread t slot s owns sorted position e=s*512+t.
// node word: [fkey:32 | birth_idx:16 | parent:16].
// Deterministic-reservation rounds (SOUND rule — both roots claimed
// unconditionally; round-4's conditional rv-claim was unsound because the
// elder-change decision can be transitively stale):
//   R: chase both roots; retire if equal; atomicMin-claim BOTH roots with e.
//   C: win iff wclaim[ru]==e && wclaim[rv]==e. Winners have pairwise-disjoint
//      root sets; if e wins, no earlier alive edge can touch its components
//      before its sequential turn (first alive edge on any connecting path
//      would have claimed ru/rv) -> commit == sequential semantics.
//   J: 2-pass pointer jumping keeps chase depth O(1).
// Progress: min-index alive edge always wins -> terminates.
__global__ __launch_bounds__(512) void uf_merge_k(
        const float* __restrict__ fvT, const unsigned int* __restrict__ suvw,
        float* __restrict__ dvT) {
    __shared__ float fvl[NPG];
    __shared__ unsigned long long node[NPG];
    __shared__ unsigned short deathl[NPG];
    __shared__ unsigned int se[EPG];
    __shared__ unsigned int wclaim[NPG];

    const int tid = threadIdx.x;
    const int g = blockIdx.x >> 3, k = blockIdx.x & 7;

    for (int i = tid; i < NPG; i += 512) {
        float val = fvT[(size_t)k * NN + (g << 10) + i];
        fvl[i] = val;
        node[i] = ((unsigned long long)fsort(val) << 32) | ((unsigned long long)(unsigned)i << 16) | (unsigned)i;
        deathl[i] = (unsigned short)i;
        wclaim[i] = ~0u;
    }
    for (int i = tid; i < EPG / 4; i += 512)
        ((uint4*)se)[i] = ((const uint4*)(suvw + (size_t)blockIdx.x * EPG))[i];
    __syncthreads();

    const unsigned int* node32 = (const unsigned int*)node;
    int ru[4], rv[4];
    unsigned long long wa[4], wb[4];
    unsigned int uvwP[4];
    unsigned int alive = 0xFu;
#pragma unroll
    for (int s = 0; s < 4; ++s) {
        unsigned int pk = se[s * 512 + tid];
        uvwP[s] = pk;
        ru[s] = (int)(pk & 1023u);
        rv[s] = (int)((pk >> 10) & 1023u);
        wa[s] = 0; wb[s] = 0;
    }

    for (;;) {
        // ---- phase R: chase roots, retire same-component, claim BOTH roots ----
#pragma unroll
        for (int s = 0; s < 4; ++s) if (alive & (1u << s)) {
            int r = ru[s];
            unsigned long long w = node[r];
            int p = (int)(w & 0xffffu);
            while (p != r) { r = p; w = node[r]; p = (int)(w & 0xffffu); }
            ru[s] = r; wa[s] = w;
            r = rv[s];
            w = node[r];
            p = (int)(w & 0xffffu);
            while (p != r) { r = p; w = node[r]; p = (int)(w & 0xffffu); }
            rv[s] = r; wb[s] = w;
            if (ru[s] == rv[s]) {
                alive &= ~(1u << s);
            } else {
                unsigned int e = (unsigned)(s * 512 + tid);
                atomicMin(&wclaim[ru[s]], e);
                atomicMin(&wclaim[rv[s]], e);
            }
        }
        __syncthreads();
        // ---- phase C: commit winners (min claim on BOTH roots) ----
#pragma unroll
        for (int s = 0; s < 4; ++s) if (alive & (1u << s)) {
            unsigned int e = (unsigned)(s * 512 + tid);
            if (wclaim[ru[s]] == e && wclaim[rv[s]] == e) {
                bool ec = (wa[s] >> 16) < (wb[s] >> 16);
                int young = ec ? (int)((wb[s] >> 16) & 0xffffu)
                               : (int)((wa[s] >> 16) & 0xffffu);
                unsigned int pk = uvwP[s];
                int ww = ((pk >> 20) & 1u) ? (int)(pk & 1023u) : (int)((pk >> 10) & 1023u);
                deathl[young] = (unsigned short)ww;
                unsigned long long nw = (wa[s] & ~0xffffULL) | (unsigned)rv[s];
                node[ru[s]] = nw;           // parent[ru] = rv (record preserved)
                if (ec) node[rv[s]] = nw;   // rv takes elder record (parent=rv)
                alive &= ~(1u << s);
            }
        }
        __syncthreads();
        // ---- reset claims for next round + phase J: 2-pass pointer jumping ----
        for (int i = tid; i < NPG; i += 512) {
            wclaim[i] = ~0u;
            unsigned long long wd = node[i];
            int pa = (int)(wd & 0xffffu);
            int gp = (int)(node32[pa * 2] & 0xffffu);
            if (gp != pa) node[i] = (wd & ~0xffffULL) | (unsigned)gp;
        }
        __syncthreads();
        for (int i = tid; i < NPG; i += 512) {
            unsigned long long wd = node[i];
            int pa = (int)(wd & 0xffffu);
            int gp = (int)(node32[pa * 2] & 0xffffu);
            if (gp != pa) node[i] = (wd & ~0xffffULL) | (unsigned)gp;
        }
        if (__syncthreads_count((int)(alive != 0u)) == 0) break;
    }
    for (int i = tid; i < NPG; i += 512)
        dvT[(size_t)k * NN + (g << 10) + i] = fvl[deathl[i]];
}

// ================= 3. h0 = relu(x0 @ W_in + b_in), x0 = interleave(fv,dvT) =================
__global__ __launch_bounds__(256, 2) void feat_k(
        const float* __restrict__ fv, const float* __restrict__ dvT,
        const float* __restrict__ W_in, const float* __restrict__ b_in,
        float* __restrict__ h0) {
    __shared__ float Ws[16][64];
    __shared__ float bs[64];
    const int tid = threadIdx.x;
    for (int i = tid; i < 1024; i += 256) Ws[i >> 6][i & 63] = W_in[i];
    if (tid < 64) bs[tid] = b_in[tid];
    __syncthreads();
    const int n = blockIdx.x * 256 + tid;
    float4 f0 = *(const float4*)&fv[(size_t)n * NF + 0];
    float4 f1 = *(const float4*)&fv[(size_t)n * NF + 4];
    float dd[8];
#pragma unroll
    for (int j = 0; j < 8; ++j) dd[j] = dvT[(size_t)j * NN + n];
    float x0[16] = { f0.x, dd[0], f0.y, dd[1], f0.z, dd[2], f0.w, dd[3],
                     f1.x, dd[4], f1.y, dd[5], f1.z, dd[6], f1.w, dd[7] };
    float out[64];
#pragma unroll
    for (int j = 0; j < 64; ++j) out[j] = bs[j];
#pragma unroll
    for (int i = 0; i < 16; ++i) {
        float a = x0[i];
#pragma unroll
        for (int j4 = 0; j4 < 16; ++j4) {
            float4 w = *(const float4*)&Ws[i][j4 * 4];
            out[j4 * 4 + 0] += a * w.x; out[j4 * 4 + 1] += a * w.y;
            out[j4 * 4 + 2] += a * w.z; out[j4 * 4 + 3] += a * w.w;
        }
    }
#pragma unroll
    for (int j4 = 0; j4 < 16; ++j4) {
        float4 o = { fmaxf(out[j4 * 4 + 0], 0.f), fmaxf(out[j4 * 4 + 1], 0.f),
                     fmaxf(out[j4 * 4 + 2], 0.f), fmaxf(out[j4 * 4 + 3], 0.f) };
        *(float4*)&h0[(size_t)n * 64 + j4 * 4] = o;
    }
}

// ================= 4. per-graph column sums of a [N,64] matrix =================
__global__ void reduce64_k(const float* __restrict__ h, float* __restrict__ s) {
    __shared__ float part[4][64];
    const int tid = threadIdx.x, g = blockIdx.x;
    const int c = tid & 63, rg = tid >> 6;
    float acc = 0.f;
    for (int r = rg; r < NPG; r += 4) acc += h[(size_t)(g * NPG + r) * 64 + c];
    part[rg][c] = acc;
    __syncthreads();
    if (tid < 64) s[g * 64 + tid] = part[0][tid] + part[1][tid] + part[2][tid] + part[3][tid];
}

// ================= 5. bias[g][j] = Gb[j] - (s[g]/1024) @ LW =================
__global__ void lam_k(const float* __restrict__ s, const float* __restrict__ LW,
                      const float* __restrict__ Gb, float* __restrict__ bias, int Fout) {
    __shared__ float sg[64];
    const int tid = threadIdx.x, g = blockIdx.x;
    if (tid < 64) sg[tid] = s[g * 64 + tid] * (1.0f / 1024.0f);
    __syncthreads();
    for (int j = tid; j < Fout; j += 256) {
        float acc = 0.f;
        for (int i = 0; i < 64; ++i) acc += sg[i] * LW[i * Fout + j];
        bias[g * Fout + j] = Gb[j] - acc;
    }
}

// ================= 6. h1 = relu(h0 @ g1W + bias1[g]) =================
__global__ __launch_bounds__(256, 2) void ds1_k(
        const float* __restrict__ h0, const float* __restrict__ g1W,
        const float* __restrict__ bias1, float* __restrict__ h1) {
    __shared__ float Ws[64][64];
    const int tid = threadIdx.x;
    for (int i = tid; i < 4096; i += 256) Ws[i >> 6][i & 63] = g1W[i];
    __syncthreads();
    const int n = blockIdx.x * 256 + tid;
    const int g = n >> 10;
    float in[64];
#pragma unroll
    for (int i4 = 0; i4 < 16; ++i4) {
        float4 t = *(const float4*)&h0[(size_t)n * 64 + i4 * 4];
        in[i4 * 4 + 0] = t.x; in[i4 * 4 + 1] = t.y; in[i4 * 4 + 2] = t.z; in[i4 * 4 + 3] = t.w;
    }
    float out[64];
#pragma unroll
    for (int j4 = 0; j4 < 16; ++j4) {
        float4 b = *(const float4*)&bias1[g * 64 + j4 * 4];
        out[j4 * 4 + 0] = b.x; out[j4 * 4 + 1] = b.y; out[j4 * 4 + 2] = b.z; out[j4 * 4 + 3] = b.w;
    }
#pragma unroll 8
    for (int i = 0; i < 64; ++i) {
        float a = in[i];
#pragma unroll
        for (int j4 = 0; j4 < 16; ++j4) {
            float4 w = *(const float4*)&Ws[i][j4 * 4];
            out[j4 * 4 + 0] += a * w.x; out[j4 * 4 + 1] += a * w.y;
            out[j4 * 4 + 2] += a * w.z; out[j4 * 4 + 3] += a * w.w;
        }
    }
#pragma unroll
    for (int j4 = 0; j4 < 16; ++j4) {
        float4 o = { fmaxf(out[j4 * 4 + 0], 0.f), fmaxf(out[j4 * 4 + 1], 0.f),
                     fmaxf(out[j4 * 4 + 2], 0.f), fmaxf(out[j4 * 4 + 3], 0.f) };
        *(float4*)&h1[(size_t)n * 64 + j4 * 4] = o;
    }
}

// ================= 7. r = relu(h1 @ g2W + bias2[g]) -> d_out =================
__global__ __launch_bounds__(256, 2) void ds2_k(
        const float* __restrict__ h1, const float* __restrict__ g2W,
        const float* __restrict__ bias2, float* __restrict__ rout) {
    __shared__ float Ht[32][68];
    __shared__ float Wt[64][68];
    const int tid = threadIdx.x;
    const int rowBase = blockIdx.x * 32;
    const int g = rowBase >> 10;
#pragma unroll
    for (int p = 0; p < 2; ++p) {
        int fid = tid + p * 256;
        int r = fid >> 4, c4 = fid & 15;
        *(float4*)&Ht[r][c4 * 4] = *(const float4*)&h1[(size_t)(rowBase + r) * 64 + c4 * 4];
    }
    const int cg = tid & 15, rg = tid >> 4;   // cols cg*4..+3, rows rg*2..+1
    for (int nc = 0; nc < 8; ++nc) {
        __syncthreads();
#pragma unroll
        for (int p = 0; p < 4; ++p) {
            int fid = tid + p * 256;
            int kk = fid >> 4, c4 = fid & 15;
            *(float4*)&Wt[kk][c4 * 4] = *(const float4*)&g2W[(size_t)kk * FEAT + nc * 64 + c4 * 4];
        }
        __syncthreads();
        float a0[4] = {0.f, 0.f, 0.f, 0.f}, a1[4] = {0.f, 0.f, 0.f, 0.f};
#pragma unroll 8
        for (int kk = 0; kk < 64; ++kk) {
            float h0v = Ht[rg * 2][kk], h1v = Ht[rg * 2 + 1][kk];
            float4 w = *(const float4*)&Wt[kk][cg * 4];
            a0[0] += h0v * w.x; a0[1] += h0v * w.y; a0[2] += h0v * w.z; a0[3] += h0v * w.w;
            a1[0] += h1v * w.x; a1[1] += h1v * w.y; a1[2] += h1v * w.z; a1[3] += h1v * w.w;
        }
        float4 bv = *(const float4*)&bias2[g * FEAT + nc * 64 + cg * 4];
        int row0 = rowBase + rg * 2;
        float4 o0 = { fmaxf(a0[0] + bv.x, 0.f), fmaxf(a0[1] + bv.y, 0.f),
                      fmaxf(a0[2] + bv.z, 0.f), fmaxf(a0[3] + bv.w, 0.f) };
        float4 o1 = { fmaxf(a1[0] + bv.x, 0.f), fmaxf(a1[1] + bv.y, 0.f),
                      fmaxf(a1[2] + bv.z, 0.f), fmaxf(a1[3] + bv.w, 0.f) };
        *(float4*)&rout[(size_t)row0 * FEAT + nc * 64 + cg * 4] = o0;
        *(float4*)&rout[(size_t)(row0 + 1) * FEAT + nc * 64 + cg * 4] = o1;
    }
}

// ================= 8. BN stats =================
__global__ void bnst1_k(const float* __restrict__ r, float* __restrict__ psum, float* __restrict__ psq) {
    const int tid = threadIdx.x, b = blockIdx.x;
    const int row0 = b * 128;
    float s0 = 0.f, q0 = 0.f, s1 = 0.f, q1 = 0.f;
    for (int rr = 0; rr < 128; ++rr) {
        float a = r[(size_t)(row0 + rr) * FEAT + tid];
        float c = r[(size_t)(row0 + rr) * FEAT + 256 + tid];
        s0 += a; q0 += a * a; s1 += c; q1 += c * c;
    }
    psum[b * FEAT + tid] = s0; psum[b * FEAT + 256 + tid] = s1;
    psq [b * FEAT + tid] = q0; psq [b * FEAT + 256 + tid] = q1;
}

__global__ void bnst2_k(const float* __restrict__ psum, const float* __restrict__ psq,
                        const float* __restrict__ gamma, const float* __restrict__ beta,
                        float* __restrict__ scsh) {
    const int tid = threadIdx.x;
    for (int c = tid; c < FEAT; c += 256) {
        float s = 0.f, q = 0.f;
        for (int b = 0; b < 256; ++b) { s += psum[b * FEAT + c]; q += psq[b * FEAT + c]; }
        float mu = s * (1.0f / (float)NN);
        float var = q * (1.0f / (float)NN) - mu * mu;
        float sc = gamma[c] * rsqrtf(var + 1e-5f);
        scsh[c] = sc;
        scsh[FEAT + c] = beta[c] - mu * sc;
    }
}

// ================= 9. out = x + r*scale + shift (in-place on d_out) =================
__global__ void final_k(const float* __restrict__ x, const float* __restrict__ scsh,
                        float* __restrict__ out) {
    const int total4 = NN * (FEAT / 4);
    for (int idx = blockIdx.x * 256 + threadIdx.x; idx < total4; idx += 2048 * 256) {
        int col4 = idx & (FEAT / 4 - 1);
        float4 rv = *(float4*)&out[(size_t)idx * 4];
        float4 xv = *(const float4*)&x[(size_t)idx * 4];
        float4 sc = *(const float4*)&scsh[col4 * 4];
        float4 sh = *(const float4*)&scsh[FEAT + col4 * 4];
        float4 o = { xv.x + rv.x * sc.x + sh.x, xv.y + rv.y * sc.y + sh.y,
                     xv.z + rv.z * sc.z + sh.z, xv.w + rv.w * sc.w + sh.w };
        *(float4*)&out[(size_t)idx * 4] = o;
    }
}

// =============================== launcher ===============================
extern "C" void kernel_launch(void* const* d_in, const int* in_sizes, int n_in,
                              void* d_out, int out_size, void* d_ws, size_t ws_size,
                              hipStream_t stream) {
    const float* x     = (const float*)d_in[0];
    const int*   ei    = (const int*)d_in[1];
    const float* W1    = (const float*)d_in[5];
    const float* b1    = (const float*)d_in[6];
    const float* W2    = (const float*)d_in[7];
    const float* b2    = (const float*)d_in[8];
    const float* W_in  = (const float*)d_in[9];
    const float* b_in  = (const float*)d_in[10];
    const float* g1W   = (const float*)d_in[11];
    const float* g1b   = (const float*)d_in[12];
    const float* l1W   = (const float*)d_in[13];
    const float* g2W   = (const float*)d_in[14];
    const float* g2b   = (const float*)d_in[15];
    const float* l2W   = (const float*)d_in[16];
    const float* gamma = (const float*)d_in[17];
    const float* beta  = (const float*)d_in[18];
    float* out = (float*)d_out;
    float* ws  = (float*)d_ws;

    float* fv    = ws;                 // 262144
    float* dvT   = ws + 262144;        // 262144  (col-major [8][N])
    float* h0    = ws + 524288;        // 2097152
    float* h1    = ws + 2621440;       // 2097152
    // fvT and suvw alias the h1 region (h1 is written only later, by ds1_k)
    float*        fvT  = ws + 2621440;                        // 262144
    unsigned int* suvw = (unsigned int*)(ws + 2883584);       // 524288 uints
    float* s1    = ws + 4718592;       // 2048
    float* bias1 = ws + 4720640;       // 2048
    float* s2    = ws + 4722688;       // 2048
    float* bias2 = ws + 4724736;       // 16384
    float* psum  = ws + 4741120;       // 131072
    float* psq   = ws + 4872192;       // 131072
    float* scsh  = ws + 5003264;       // 1024

    hipLaunchKernelGGL(gemm_fv_k,  dim3(512),  dim3(256), 0, stream, x, W1, b1, W2, b2, fv, fvT);
    hipLaunchKernelGGL(uf_sort_k,  dim3(256),  dim3(512), 0, stream, fvT, ei, suvw);
    hipLaunchKernelGGL(uf_merge_k, dim3(256),  dim3(512), 0, stream, fvT, suvw, dvT);
    hipLaunchKernelGGL(feat_k,     dim3(128),  dim3(256), 0, stream, fv, dvT, W_in, b_in, h0);
    hipLaunchKernelGGL(reduce64_k, dim3(32),   dim3(256), 0, stream, h0, s1);
    hipLaunchKernelGGL(lam_k,      dim3(32),   dim3(256), 0, stream, s1, l1W, g1b, bias1, 64);
    hipLaunchKernelGGL(ds1_k,      dim3(128),  dim3(256), 0, stream, h0, g1W, bias1, h1);
    hipLaunchKernelGGL(reduce64_k, dim3(32),   dim3(256), 0, stream, h1, s2);
    hipLaunchKernelGGL(lam_k,      dim3(32),   dim3(256), 0, stream, s2, l2W, g2b, bias2, 512);
    hipLaunchKernelGGL(ds2_k,      dim3(1024), dim3(256), 0, stream, h1, g2W, bias2, out);
    hipLaunchKernelGGL(bnst1_k,    dim3(256),  dim3(256), 0, stream, out, psum, psq);
    hipLaunchKernelGGL(bnst2_k,    dim3(1),    dim3(256), 0, stream, psum, psq, gamma, beta, scsh);
    hipLaunchKernelGGL(final_k,    dim3(2048), dim3(256), 0, stream, x, scsh, out);
}

// Round 7
// 869.493 us; speedup vs baseline: 2.7538x; 2.7538x over previous
//
#include <hip/hip_runtime.h>
#include <stdint.h>

// ---------------- problem constants (fixed by setup_inputs) ----------------
static constexpr int NN    = 32768;   // nodes
static constexpr int NPG   = 1024;    // nodes per graph
static constexpr int EPG   = 2048;    // edges per graph
static constexpr int NGR   = 32;      // graphs
static constexpr int NF    = 8;       // filtrations
static constexpr int FEAT  = 512;
static constexpr int ODIM  = 64;
static constexpr int ETOT  = NGR * EPG;

// order-preserving float -> uint key
__device__ __forceinline__ unsigned int fsort(float f) {
    unsigned int u = __float_as_uint(f);
    return (u & 0x80000000u) ? ~u : (u | 0x80000000u);
}

__device__ __forceinline__ unsigned long long shfl64(unsigned long long x, int src) {
    unsigned int lo = __shfl((unsigned int)x, src);
    unsigned int hi = __shfl((unsigned int)(x >> 32), src);
    return ((unsigned long long)hi << 32) | lo;
}

// ======================= 1. fv = relu(x@W1+b1)@W2+b2 =======================
// grid 512 blocks (64 rows each), 256 threads. f32 vector FMA.
// Writes fv row-major [N][8] (for feat_k) AND fvT col-major [8][N] (for uf).
__global__ __launch_bounds__(256, 2) void gemm_fv_k(
        const float* __restrict__ x,  const float* __restrict__ W1,
        const float* __restrict__ b1, const float* __restrict__ W2,
        const float* __restrict__ b2, float* __restrict__ fv,
        float* __restrict__ fvT) {
    __shared__ float As[64][68];   // As[k][r] transposed x tile
    __shared__ float Bs[64][68];   // Bs[k][c] W1 tile
    __shared__ float W2s[64][8];

    const int tid = threadIdx.x;
    const int tx = tid & 15;       // col group: cols tx*4..+3
    const int ty = tid >> 4;       // row group: rows ty*4..+3
    const int rowBase = blockIdx.x * 64;

    float fvacc[4][8];
#pragma unroll
    for (int r = 0; r < 4; ++r)
#pragma unroll
        for (int j = 0; j < 8; ++j) fvacc[r][j] = 0.f;

    for (int cc = 0; cc < 8; ++cc) {           // 64-col chunk of W1
        float hacc[4][4];
#pragma unroll
        for (int r = 0; r < 4; ++r)
#pragma unroll
            for (int c = 0; c < 4; ++c) hacc[r][c] = 0.f;

        for (int kt = 0; kt < 8; ++kt) {       // K tile of 64
#pragma unroll
            for (int p = 0; p < 4; ++p) {
                int fid = tid + p * 256;
                int rr = fid >> 4, c4 = fid & 15;
                float4 av = *(const float4*)&x[(size_t)(rowBase + rr) * FEAT + kt * 64 + c4 * 4];
                As[c4 * 4 + 0][rr] = av.x; As[c4 * 4 + 1][rr] = av.y;
                As[c4 * 4 + 2][rr] = av.z; As[c4 * 4 + 3][rr] = av.w;
                float4 bv = *(const float4*)&W1[(size_t)(kt * 64 + rr) * FEAT + cc * 64 + c4 * 4];
                *(float4*)&Bs[rr][c4 * 4] = bv;
            }
            if (kt == 0) {
#pragma unroll
                for (int p = 0; p < 2; ++p) {
                    int idx = tid + p * 256;          // 512 entries
                    int cw = idx >> 3, j = idx & 7;
                    W2s[cw][j] = W2[(cc * 64 + cw) * NF + j];
                }
            }
            __syncthreads();
#pragma unroll 8
            for (int kk = 0; kk < 64; ++kk) {
                float4 a4 = *(const float4*)&As[kk][ty * 4];
                float4 b4 = *(const float4*)&Bs[kk][tx * 4];
                hacc[0][0] += a4.x * b4.x; hacc[0][1] += a4.x * b4.y; hacc[0][2] += a4.x * b4.z; hacc[0][3] += a4.x * b4.w;
                hacc[1][0] += a4.y * b4.x; hacc[1][1] += a4.y * b4.y; hacc[1][2] += a4.y * b4.z; hacc[1][3] += a4.y * b4.w;
                hacc[2][0] += a4.z * b4.x; hacc[2][1] += a4.z * b4.y; hacc[2][2] += a4.z * b4.z; hacc[2][3] += a4.z * b4.w;
                hacc[3][0] += a4.w * b4.x; hacc[3][1] += a4.w * b4.y; hacc[3][2] += a4.w * b4.z; hacc[3][3] += a4.w * b4.w;
            }
            __syncthreads();
        }
        // relu(hacc + b1) @ W2 -> partial fv, reduced over the 16 tx lanes
        float4 b1v = *(const float4*)&b1[cc * 64 + tx * 4];
        float pf[4][8];
#pragma unroll
        for (int r = 0; r < 4; ++r)
#pragma unroll
            for (int j = 0; j < 8; ++j) pf[r][j] = 0.f;
#pragma unroll
        for (int c = 0; c < 4; ++c) {
            float bc = (c == 0) ? b1v.x : (c == 1) ? b1v.y : (c == 2) ? b1v.z : b1v.w;
            float4 w0 = *(const float4*)&W2s[tx * 4 + c][0];
            float4 w1 = *(const float4*)&W2s[tx * 4 + c][4];
#pragma unroll
            for (int r = 0; r < 4; ++r) {
                float h = fmaxf(hacc[r][c] + bc, 0.f);
                pf[r][0] += h * w0.x; pf[r][1] += h * w0.y; pf[r][2] += h * w0.z; pf[r][3] += h * w0.w;
                pf[r][4] += h * w1.x; pf[r][5] += h * w1.y; pf[r][6] += h * w1.z; pf[r][7] += h * w1.w;
            }
        }
#pragma unroll
        for (int m = 1; m <= 8; m <<= 1)
#pragma unroll
            for (int r = 0; r < 4; ++r)
#pragma unroll
                for (int j = 0; j < 8; ++j) pf[r][j] += __shfl_xor(pf[r][j], m);
#pragma unroll
        for (int r = 0; r < 4; ++r)
#pragma unroll
            for (int j = 0; j < 8; ++j) fvacc[r][j] += pf[r][j];
        __syncthreads();   // protect As/Bs/W2s before next chunk
    }
    if (tx == 0) {
        float b2a[8];
        *(float4*)&b2a[0] = *(const float4*)&b2[0];
        *(float4*)&b2a[4] = *(const float4*)&b2[4];
        float vals[4][8];
#pragma unroll
        for (int r = 0; r < 4; ++r)
#pragma unroll
            for (int j = 0; j < 8; ++j) vals[r][j] = fvacc[r][j] + b2a[j];
#pragma unroll
        for (int r = 0; r < 4; ++r) {
            int row = rowBase + ty * 4 + r;
            float4 o0 = { vals[r][0], vals[r][1], vals[r][2], vals[r][3] };
            float4 o1 = { vals[r][4], vals[r][5], vals[r][6], vals[r][7] };
            *(float4*)&fv[(size_t)row * NF + 0] = o0;
            *(float4*)&fv[(size_t)row * NF + 4] = o1;
        }
#pragma unroll
        for (int j = 0; j < 8; ++j) {
            float4 t = { vals[0][j], vals[1][j], vals[2][j], vals[3][j] };
            *(float4*)&fvT[(size_t)j * NN + rowBase + ty * 4] = t;
        }
    }
}

// ============ 2a. per-(graph,filtration) edge key build + bitonic sort ============
// grid 256 blocks (g = b>>3, k = b&7), 512 threads. Writes sorted uvw stream.
__global__ __launch_bounds__(512) void uf_sort_k(
        const float* __restrict__ fvT, const int* __restrict__ ei,
        unsigned int* __restrict__ suvw) {
    __shared__ float fvl[NPG];
    __shared__ unsigned long long keys[EPG];   // (fe_key<<32) | e  (stable tie-break)
    __shared__ unsigned int uvw[EPG];          // u | v<<10 | wflag<<20
    const int tid = threadIdx.x;
    const int g = blockIdx.x >> 3, k = blockIdx.x & 7;

    for (int i = tid; i < NPG; i += 512) fvl[i] = fvT[(size_t)k * NN + (g << 10) + i];
    __syncthreads();
    for (int e = tid; e < EPG; e += 512) {
        int eg = g * EPG + e;
        int u = ei[eg] & (NPG - 1);
        int v = ei[ETOT + eg] & (NPG - 1);
        unsigned int fku = fsort(fvl[u]);
        unsigned int fkv = fsort(fvl[v]);
        unsigned int wfl = (fku > fkv || (fku == fkv && u >= v)) ? 1u : 0u;  // w = u iff (fv[u],u) >= (fv[v],v)
        unsigned int fe = fku > fkv ? fku : fkv;
        uvw[e] = (unsigned)u | ((unsigned)v << 10) | (wfl << 20);
        keys[e] = ((unsigned long long)fe << 32) | (unsigned)e;
    }
    for (int size = 2; size <= EPG; size <<= 1) {
        for (int stride = size >> 1; stride > 0; stride >>= 1) {
            __syncthreads();
            for (int i = tid; i < EPG; i += 512) {
                int j = i ^ stride;
                if (j > i) {
                    unsigned long long a = keys[i], b = keys[j];
                    bool asc = (i & size) == 0;
                    if (asc ? (a > b) : (a < b)) { keys[i] = b; keys[j] = a; }
                }
            }
        }
    }
    __syncthreads();
    for (int i = tid; i < EPG; i += 512)
        suvw[(size_t)blockIdx.x * EPG + i] = uvw[(unsigned)(keys[i] & 0xffffffffULL)];
}

// ============ 2b. EXACT sequential union-find at wave speed ============
// grid 256 blocks, 256 threads (staging + output); wave 0 executes the merge.
// node word: [fkey:32 | birth_idx:16 | parent:16]. UNION-BY-ELDER: young root
// links under elder root; elder root's record is invariant.
// Per window of 64 sorted edges: (a) 64 lanes chase both roots in parallel
// (path-halving via low-dword writes); (b) intra-wave commit loop, exact
// sequential order: ballot alive lanes, lowest lane li commits (deathl +
// node[young]=link), everyone receives (ru,rv,wa,wb,w) via shuffles (li is
// wave-uniform -> readlane) and patches cached roots/records in registers:
// root==young -> root=elder, rec=elder_rec (invariant!), retire on equality.
// No approximation: this IS the reference loop, state broadcast in registers.
__global__ __launch_bounds__(256) void uf_merge_k(
        const float* __restrict__ fvT, const unsigned int* __restrict__ suvw,
        float* __restrict__ dvT) {
    __shared__ float fvl[NPG];
    __shared__ unsigned long long node[NPG];
    __shared__ unsigned short deathl[NPG];
    __shared__ unsigned int se[EPG];

    const int tid = threadIdx.x;
    const int g = blockIdx.x >> 3, k = blockIdx.x & 7;

    for (int i = tid; i < NPG; i += 256) {
        float val = fvT[(size_t)k * NN + (g << 10) + i];
        fvl[i] = val;
        node[i] = ((unsigned long long)fsort(val) << 32) | ((unsigned long long)(unsigned)i << 16) | (unsigned)i;
        deathl[i] = (unsigned short)i;
    }
    for (int i = tid; i < EPG / 4; i += 256)
        ((uint4*)se)[i] = ((const uint4*)(suvw + (size_t)blockIdx.x * EPG))[i];
    __syncthreads();

    if (tid < 64) {
        const int lane = tid;
        volatile unsigned int* vn32 = (volatile unsigned int*)node;
        volatile unsigned long long* vn64 = (volatile unsigned long long*)node;
        for (int w = 0; w < EPG / 64; ++w) {
            unsigned int pk = se[w * 64 + lane];
            int u = (int)(pk & 1023u), v = (int)((pk >> 10) & 1023u);
            int wd = ((pk >> 20) & 1u) ? u : v;       // death vertex (static)
            // chase with path-halving (low-dword writes preserve birth bits)
            int ru = u;
            {
                unsigned int lw = vn32[ru * 2];
                int p = (int)(lw & 0xffffu);
                while (p != ru) {
                    unsigned int lw2 = vn32[p * 2];
                    int gp = (int)(lw2 & 0xffffu);
                    if (gp != p) vn32[ru * 2] = (lw & 0xffff0000u) | (unsigned)gp;
                    ru = p; lw = lw2; p = gp;
                }
            }
            int rv = v;
            {
                unsigned int lw = vn32[rv * 2];
                int p = (int)(lw & 0xffffu);
                while (p != rv) {
                    unsigned int lw2 = vn32[p * 2];
                    int gp = (int)(lw2 & 0xffffu);
                    if (gp != p) vn32[rv * 2] = (lw & 0xffff0000u) | (unsigned)gp;
                    rv = p; lw = lw2; p = gp;
                }
            }
            unsigned long long wa = vn64[ru];
            unsigned long long wb = vn64[rv];
            bool aliveF = (ru != rv);
            unsigned long long mask = __ballot(aliveF);
            while (mask) {
                int li = (int)__builtin_ctzll(mask);   // lowest alive lane = sorted order
                int bru = __shfl(ru, li), brv = __shfl(rv, li);
                unsigned long long bwa = shfl64(wa, li), bwb = shfl64(wb, li);
                int bw = __shfl(wd, li);
                bool uE = (bwa >> 16) <= (bwb >> 16);  // (fkey,birth) lex compare
                int rE = uE ? bru : brv;
                int rY = uE ? brv : bru;
                unsigned long long wE = uE ? bwa : bwb;
                unsigned long long wY = uE ? bwb : bwa;
                if (lane == li) {
                    deathl[(int)((wY >> 16) & 0xffffu)] = (unsigned short)bw;
                    vn64[rY] = (wY & ~0xffffULL) | (unsigned)rE;
                }
                if (ru == rY) { ru = rE; wa = wE; }
                if (rv == rY) { rv = rE; wb = wE; }
                aliveF = aliveF && (lane > li) && (ru != rv);
                mask = __ballot(aliveF);
            }
            __builtin_amdgcn_wave_barrier();
        }
    }
    __syncthreads();
    for (int i = tid; i < NPG; i += 256)
        dvT[(size_t)k * NN + (g << 10) + i] = fvl[deathl[i]];
}

// ================= 3. h0 = relu(x0 @ W_in + b_in), x0 = interleave(fv,dvT) =================
__global__ __launch_bounds__(256, 2) void feat_k(
        const float* __restrict__ fv, const float* __restrict__ dvT,
        const float* __restrict__ W_in, const float* __restrict__ b_in,
        float* __restrict__ h0) {
    __shared__ float Ws[16][64];
    __shared__ float bs[64];
    const int tid = threadIdx.x;
    for (int i = tid; i < 1024; i += 256) Ws[i >> 6][i & 63] = W_in[i];
    if (tid < 64) bs[tid] = b_in[tid];
    __syncthreads();
    const int n = blockIdx.x * 256 + tid;
    float4 f0 = *(const float4*)&fv[(size_t)n * NF + 0];
    float4 f1 = *(const float4*)&fv[(size_t)n * NF + 4];
    float dd[8];
#pragma unroll
    for (int j = 0; j < 8; ++j) dd[j] = dvT[(size_t)j * NN + n];
    float x0[16] = { f0.x, dd[0], f0.y, dd[1], f0.z, dd[2], f0.w, dd[3],
                     f1.x, dd[4], f1.y, dd[5], f1.z, dd[6], f1.w, dd[7] };
    float out[64];
#pragma unroll
    for (int j = 0; j < 64; ++j) out[j] = bs[j];
#pragma unroll
    for (int i = 0; i < 16; ++i) {
        float a = x0[i];
#pragma unroll
        for (int j4 = 0; j4 < 16; ++j4) {
            float4 w = *(const float4*)&Ws[i][j4 * 4];
            out[j4 * 4 + 0] += a * w.x; out[j4 * 4 + 1] += a * w.y;
            out[j4 * 4 + 2] += a * w.z; out[j4 * 4 + 3] += a * w.w;
        }
    }
#pragma unroll
    for (int j4 = 0; j4 < 16; ++j4) {
        float4 o = { fmaxf(out[j4 * 4 + 0], 0.f), fmaxf(out[j4 * 4 + 1], 0.f),
                     fmaxf(out[j4 * 4 + 2], 0.f), fmaxf(out[j4 * 4 + 3], 0.f) };
        *(float4*)&h0[(size_t)n * 64 + j4 * 4] = o;
    }
}

// ================= 4. per-graph column sums of a [N,64] matrix =================
__global__ void reduce64_k(const float* __restrict__ h, float* __restrict__ s) {
    __shared__ float part[4][64];
    const int tid = threadIdx.x, g = blockIdx.x;
    const int c = tid & 63, rg = tid >> 6;
    float acc = 0.f;
    for (int r = rg; r < NPG; r += 4) acc += h[(size_t)(g * NPG + r) * 64 + c];
    part[rg][c] = acc;
    __syncthreads();
    if (tid < 64) s[g * 64 + tid] = part[0][tid] + part[1][tid] + part[2][tid] + part[3][tid];
}

// ================= 5. bias[g][j] = Gb[j] - (s[g]/1024) @ LW =================
__global__ void lam_k(const float* __restrict__ s, const float* __restrict__ LW,
                      const float* __restrict__ Gb, float* __restrict__ bias, int Fout) {
    __shared__ float sg[64];
    const int tid = threadIdx.x, g = blockIdx.x;
    if (tid < 64) sg[tid] = s[g * 64 + tid] * (1.0f / 1024.0f);
    __syncthreads();
    for (int j = tid; j < Fout; j += 256) {
        float acc = 0.f;
        for (int i = 0; i < 64; ++i) acc += sg[i] * LW[i * Fout + j];
        bias[g * Fout + j] = Gb[j] - acc;
    }
}

// ================= 6. h1 = relu(h0 @ g1W + bias1[g]) =================
__global__ __launch_bounds__(256, 2) void ds1_k(
        const float* __restrict__ h0, const float* __restrict__ g1W,
        const float* __restrict__ bias1, float* __restrict__ h1) {
    __shared__ float Ws[64][64];
    const int tid = threadIdx.x;
    for (int i = tid; i < 4096; i += 256) Ws[i >> 6][i & 63] = g1W[i];
    __syncthreads();
    const int n = blockIdx.x * 256 + tid;
    const int g = n >> 10;
    float in[64];
#pragma unroll
    for (int i4 = 0; i4 < 16; ++i4) {
        float4 t = *(const float4*)&h0[(size_t)n * 64 + i4 * 4];
        in[i4 * 4 + 0] = t.x; in[i4 * 4 + 1] = t.y; in[i4 * 4 + 2] = t.z; in[i4 * 4 + 3] = t.w;
    }
    float out[64];
#pragma unroll
    for (int j4 = 0; j4 < 16; ++j4) {
        float4 b = *(const float4*)&bias1[g * 64 + j4 * 4];
        out[j4 * 4 + 0] = b.x; out[j4 * 4 + 1] = b.y; out[j4 * 4 + 2] = b.z; out[j4 * 4 + 3] = b.w;
    }
#pragma unroll 8
    for (int i = 0; i < 64; ++i) {
        float a = in[i];
#pragma unroll
        for (int j4 = 0; j4 < 16; ++j4) {
            float4 w = *(const float4*)&Ws[i][j4 * 4];
            out[j4 * 4 + 0] += a * w.x; out[j4 * 4 + 1] += a * w.y;
            out[j4 * 4 + 2] += a * w.z; out[j4 * 4 + 3] += a * w.w;
        }
    }
#pragma unroll
    for (int j4 = 0; j4 < 16; ++j4) {
        float4 o = { fmaxf(out[j4 * 4 + 0], 0.f), fmaxf(out[j4 * 4 + 1], 0.f),
                     fmaxf(out[j4 * 4 + 2], 0.f), fmaxf(out[j4 * 4 + 3], 0.f) };
        *(float4*)&h1[(size_t)n * 64 + j4 * 4] = o;
    }
}

// ================= 7. r = relu(h1 @ g2W + bias2[g]) -> d_out =================
__global__ __launch_bounds__(256, 2) void ds2_k(
        const float* __restrict__ h1, const float* __restrict__ g2W,
        const float* __restrict__ bias2, float* __restrict__ rout) {
    __shared__ float Ht[32][68];
    __shared__ float Wt[64][68];
    const int tid = threadIdx.x;
    const int rowBase = blockIdx.x * 32;
    const int g = rowBase >> 10;
#pragma unroll
    for (int p = 0; p < 2; ++p) {
        int fid = tid + p * 256;
        int r = fid >> 4, c4 = fid & 15;
        *(float4*)&Ht[r][c4 * 4] = *(const float4*)&h1[(size_t)(rowBase + r) * 64 + c4 * 4];
    }
    const int cg = tid & 15, rg = tid >> 4;   // cols cg*4..+3, rows rg*2..+1
    for (int nc = 0; nc < 8; ++nc) {
        __syncthreads();
#pragma unroll
        for (int p = 0; p < 4; ++p) {
            int fid = tid + p * 256;
            int kk = fid >> 4, c4 = fid & 15;
            *(float4*)&Wt[kk][c4 * 4] = *(const float4*)&g2W[(size_t)kk * FEAT + nc * 64 + c4 * 4];
        }
        __syncthreads();
        float a0[4] = {0.f, 0.f, 0.f, 0.f}, a1[4] = {0.f, 0.f, 0.f, 0.f};
#pragma unroll 8
        for (int kk = 0; kk < 64; ++kk) {
            float h0v = Ht[rg * 2][kk], h1v = Ht[rg * 2 + 1][kk];
            float4 w = *(const float4*)&Wt[kk][cg * 4];
            a0[0] += h0v * w.x; a0[1] += h0v * w.y; a0[2] += h0v * w.z; a0[3] += h0v * w.w;
            a1[0] += h1v * w.x; a1[1] += h1v * w.y; a1[2] += h1v * w.z; a1[3] += h1v * w.w;
        }
        float4 bv = *(const float4*)&bias2[g * FEAT + nc * 64 + cg * 4];
        int row0 = rowBase + rg * 2;
        float4 o0 = { fmaxf(a0[0] + bv.x, 0.f), fmaxf(a0[1] + bv.y, 0.f),
                      fmaxf(a0[2] + bv.z, 0.f), fmaxf(a0[3] + bv.w, 0.f) };
        float4 o1 = { fmaxf(a1[0] + bv.x, 0.f), fmaxf(a1[1] + bv.y, 0.f),
                      fmaxf(a1[2] + bv.z, 0.f), fmaxf(a1[3] + bv.w, 0.f) };
        *(float4*)&rout[(size_t)row0 * FEAT + nc * 64 + cg * 4] = o0;
        *(float4*)&rout[(size_t)(row0 + 1) * FEAT + nc * 64 + cg * 4] = o1;
    }
}

// ================= 8. BN stats =================
__global__ void bnst1_k(const float* __restrict__ r, float* __restrict__ psum, float* __restrict__ psq) {
    const int tid = threadIdx.x, b = blockIdx.x;
    const int row0 = b * 128;
    float s0 = 0.f, q0 = 0.f, s1 = 0.f, q1 = 0.f;
    for (int rr = 0; rr < 128; ++rr) {
        float a = r[(size_t)(row0 + rr) * FEAT + tid];
        float c = r[(size_t)(row0 + rr) * FEAT + 256 + tid];
        s0 += a; q0 += a * a; s1 += c; q1 += c * c;
    }
    psum[b * FEAT + tid] = s0; psum[b * FEAT + 256 + tid] = s1;
    psq [b * FEAT + tid] = q0; psq [b * FEAT + 256 + tid] = q1;
}

__global__ void bnst2_k(const float* __restrict__ psum, const float* __restrict__ psq,
                        const float* __restrict__ gamma, const float* __restrict__ beta,
                        float* __restrict__ scsh) {
    const int tid = threadIdx.x;
    for (int c = tid; c < FEAT; c += 256) {
        float s = 0.f, q = 0.f;
        for (int b = 0; b < 256; ++b) { s += psum[b * FEAT + c]; q += psq[b * FEAT + c]; }
        float mu = s * (1.0f / (float)NN);
        float var = q * (1.0f / (float)NN) - mu * mu;
        float sc = gamma[c] * rsqrtf(var + 1e-5f);
        scsh[c] = sc;
        scsh[FEAT + c] = beta[c] - mu * sc;
    }
}

// ================= 9. out = x + r*scale + shift (in-place on d_out) =================
__global__ void final_k(const float* __restrict__ x, const float* __restrict__ scsh,
                        float* __restrict__ out) {
    const int total4 = NN * (FEAT / 4);
    for (int idx = blockIdx.x * 256 + threadIdx.x; idx < total4; idx += 2048 * 256) {
        int col4 = idx & (FEAT / 4 - 1);
        float4 rv = *(float4*)&out[(size_t)idx * 4];
        float4 xv = *(const float4*)&x[(size_t)idx * 4];
        float4 sc = *(const float4*)&scsh[col4 * 4];
        float4 sh = *(const float4*)&scsh[FEAT + col4 * 4];
        float4 o = { xv.x + rv.x * sc.x + sh.x, xv.y + rv.y * sc.y + sh.y,
                     xv.z + rv.z * sc.z + sh.z, xv.w + rv.w * sc.w + sh.w };
        *(float4*)&out[(size_t)idx * 4] = o;
    }
}

// =============================== launcher ===============================
extern "C" void kernel_launch(void* const* d_in, const int* in_sizes, int n_in,
                              void* d_out, int out_size, void* d_ws, size_t ws_size,
                              hipStream_t stream) {
    const float* x     = (const float*)d_in[0];
    const int*   ei    = (const int*)d_in[1];
    const float* W1    = (const float*)d_in[5];
    const float* b1    = (const float*)d_in[6];
    const float* W2    = (const float*)d_in[7];
    const float* b2    = (const float*)d_in[8];
    const float* W_in  = (const float*)d_in[9];
    const float* b_in  = (const float*)d_in[10];
    const float* g1W   = (const float*)d_in[11];
    const float* g1b   = (const float*)d_in[12];
    const float* l1W   = (const float*)d_in[13];
    const float* g2W   = (const float*)d_in[14];
    const float* g2b   = (const float*)d_in[15];
    const float* l2W   = (const float*)d_in[16];
    const float* gamma = (const float*)d_in[17];
    const float* beta  = (const float*)d_in[18];
    float* out = (float*)d_out;
    float* ws  = (float*)d_ws;

    float* fv    = ws;                 // 262144
    float* dvT   = ws + 262144;        // 262144  (col-major [8][N])
    float* h0    = ws + 524288;        // 2097152
    float* h1    = ws + 2621440;       // 2097152
    // fvT and suvw alias the h1 region (h1 is written only later, by ds1_k)
    float*        fvT  = ws + 2621440;                        // 262144
    unsigned int* suvw = (unsigned int*)(ws + 2883584);       // 524288 uints
    float* s1    = ws + 4718592;       // 2048
    float* bias1 = ws + 4720640;       // 2048
    float* s2    = ws + 4722688;       // 2048
    float* bias2 = ws + 4724736;       // 16384
    float* psum  = ws + 4741120;       // 131072
    float* psq   = ws + 4872192;       // 131072
    float* scsh  = ws + 5003264;       // 1024

    hipLaunchKernelGGL(gemm_fv_k,  dim3(512),  dim3(256), 0, stream, x, W1, b1, W2, b2, fv, fvT);
    hipLaunchKernelGGL(uf_sort_k,  dim3(256),  dim3(512), 0, stream, fvT, ei, suvw);
    hipLaunchKernelGGL(uf_merge_k, dim3(256),  dim3(256), 0, stream, fvT, suvw, dvT);
    hipLaunchKernelGGL(feat_k,     dim3(128),  dim3(256), 0, stream, fv, dvT, W_in, b_in, h0);
    hipLaunchKernelGGL(reduce64_k, dim3(32),   dim3(256), 0, stream, h0, s1);
    hipLaunchKernelGGL(lam_k,      dim3(32),   dim3(256), 0, stream, s1, l1W, g1b, bias1, 64);
    hipLaunchKernelGGL(ds1_k,      dim3(128),  dim3(256), 0, stream, h0, g1W, bias1, h1);
    hipLaunchKernelGGL(reduce64_k, dim3(32),   dim3(256), 0, stream, h1, s2);
    hipLaunchKernelGGL(lam_k,      dim3(32),   dim3(256), 0, stream, s2, l2W, g2b, bias2, 512);
    hipLaunchKernelGGL(ds2_k,      dim3(1024), dim3(256), 0, stream, h1, g2W, bias2, out);
    hipLaunchKernelGGL(bnst1_k,    dim3(256),  dim3(256), 0, stream, out, psum, psq);
    hipLaunchKernelGGL(bnst2_k,    dim3(1),    dim3(256), 0, stream, psum, psq, gamma, beta, scsh);
    hipLaunchKernelGGL(final_k,    dim3(2048), dim3(256), 0, stream, x, scsh, out);
}